// Round 1
// baseline (993.867 us; speedup 1.0000x reference)
//
#include <hip/hip_runtime.h>
#include <math.h>

#define NROWS 32768
#define DIM   256
#define KCODES 1024

// ws layout:
//   [0, 8)          double loss accumulator
//   [8, 8+4096)     se[1024]  float   (np-exact pairwise sum of codebook**2 rows)
//   [4104, +131072) sx[32768] float   (np-exact pairwise sum of x**2 rows)

__global__ void init_ws(double* acc) {
    if (threadIdx.x == 0 && blockIdx.x == 0) *acc = 0.0;
}

// Bit-exact replication of numpy pairwise_sum_FLOAT for n=256 contiguous floats
// (sum of squares of each row). numpy: n=256 -> pw(0,128)+pw(128,128); each 128-block:
// 8 accumulators r[j] summed sequentially over 16 strided terms, combined as
// ((r0+r1)+(r2+r3))+((r4+r5)+(r6+r7)). We map: wave = 4 rows x 16 agents
// (agent = half*8+j); each agent does its sequential 16-term chain; the combine
// tree is an xor-butterfly (IEEE add commutative => bitwise identical).
__global__ void rowsq_kernel(const float* __restrict__ src,
                             float* __restrict__ dst, int nrows) {
    const int gtid = blockIdx.x * blockDim.x + threadIdx.x;
    const int wave = gtid >> 6;
    const int lane = threadIdx.x & 63;
    const int rowsub = lane >> 4;     // 0..3
    const int agent  = lane & 15;     // half*8 + j
    const int half   = agent >> 3;
    const int j      = agent & 7;
    const int row = wave * 4 + rowsub;
    if (row >= nrows) return;

    const float* p = src + (size_t)row * DIM + half * 128 + j;
    float x0 = p[0];
    float r = __fmul_rn(x0, x0);
    #pragma unroll
    for (int i = 1; i < 16; ++i) {
        float xi = p[8 * i];
        r = __fadd_rn(r, __fmul_rn(xi, xi));
    }
    // combine 8 accumulators: ((r0+r1)+(r2+r3))+((r4+r5)+(r6+r7))
    r = __fadd_rn(r, __shfl_xor(r, 1, 64));
    r = __fadd_rn(r, __shfl_xor(r, 2, 64));
    r = __fadd_rn(r, __shfl_xor(r, 4, 64));
    // top-level: pw(first 128) + pw(second 128)
    r = __fadd_rn(r, __shfl_xor(r, 8, 64));
    if (agent == 0) dst[row] = r;
}

#define FMA4(A, X, E)                                            \
    A.x = fmaf(X.x, E.x, A.x); A.y = fmaf(X.y, E.y, A.y);        \
    A.z = fmaf(X.z, E.z, A.z); A.w = fmaf(X.w, E.w, A.w);

__launch_bounds__(256)
__global__ void vq_main(const float* __restrict__ x,
                        const float* __restrict__ cb,
                        const float* __restrict__ sx_arr,
                        const float* __restrict__ se_arr,
                        float* __restrict__ out_q,
                        float* __restrict__ out_idx,
                        double* __restrict__ loss_acc) {
    __shared__ float4 xs4[64 * 64];   // 64 rows x 256 floats = 64 KiB
    const int tid = threadIdx.x;
    const int n0  = blockIdx.x * 64;
    const float4* __restrict__ x4  = (const float4*)x;
    const float4* __restrict__ cb4 = (const float4*)cb;

    // stage 64-row x tile (coalesced float4)
    #pragma unroll
    for (int it = 0; it < 16; ++it) {
        int idx = it * 256 + tid;
        xs4[idx] = x4[(size_t)n0 * 64 + idx];
    }
    __syncthreads();

    const int rq = tid >> 4;   // 0..15 -> rows rq*4 .. rq*4+3
    const int kq = tid & 15;   // 0..15 -> codes [kq*64, kq*64+64)

    float sx[4], best[4];
    int bidx[4];
    #pragma unroll
    for (int i = 0; i < 4; ++i) {
        sx[i] = sx_arr[n0 + rq * 4 + i];
        best[i] = INFINITY;
        bidx[i] = 0;
    }

    for (int j0 = 0; j0 < 64; j0 += 4) {
        const int k0 = kq * 64 + j0;
        float4 acc[4][4];
        #pragma unroll
        for (int i = 0; i < 4; ++i)
            #pragma unroll
            for (int c = 0; c < 4; ++c)
                acc[i][c] = make_float4(0.f, 0.f, 0.f, 0.f);

        const float4* cbp = cb4 + (size_t)k0 * 64;
        #pragma unroll 4
        for (int d4 = 0; d4 < 64; ++d4) {
            float4 ev0 = cbp[d4];
            float4 ev1 = cbp[64 + d4];
            float4 ev2 = cbp[128 + d4];
            float4 ev3 = cbp[192 + d4];
            float4 xv0 = xs4[(rq * 4 + 0) * 64 + d4];
            float4 xv1 = xs4[(rq * 4 + 1) * 64 + d4];
            float4 xv2 = xs4[(rq * 4 + 2) * 64 + d4];
            float4 xv3 = xs4[(rq * 4 + 3) * 64 + d4];
            FMA4(acc[0][0], xv0, ev0); FMA4(acc[0][1], xv0, ev1);
            FMA4(acc[0][2], xv0, ev2); FMA4(acc[0][3], xv0, ev3);
            FMA4(acc[1][0], xv1, ev0); FMA4(acc[1][1], xv1, ev1);
            FMA4(acc[1][2], xv1, ev2); FMA4(acc[1][3], xv1, ev3);
            FMA4(acc[2][0], xv2, ev0); FMA4(acc[2][1], xv2, ev1);
            FMA4(acc[2][2], xv2, ev2); FMA4(acc[2][3], xv2, ev3);
            FMA4(acc[3][0], xv3, ev0); FMA4(acc[3][1], xv3, ev1);
            FMA4(acc[3][2], xv3, ev2); FMA4(acc[3][3], xv3, ev3);
        }

        #pragma unroll
        for (int c = 0; c < 4; ++c) {
            const int kk = k0 + c;
            const float se = se_arr[kk];
            #pragma unroll
            for (int i = 0; i < 4; ++i) {
                float4 a = acc[i][c];
                float dot = (a.x + a.y) + (a.z + a.w);      // order-insensitive part
                float t = __fadd_rn(sx[i], se);             // fl(sx + se), np assoc
                float dist = __fsub_rn(t, 2.0f * dot);      // fl(t - 2*dot); 2*dot exact
                if (dist < best[i]) { best[i] = dist; bidx[i] = kk; }  // first-min
            }
        }
    }

    // cross-kq argmin reduce (16 lanes per row group, within-wave), tie -> lower k
    #pragma unroll
    for (int i = 0; i < 4; ++i) {
        float b = best[i]; int bi = bidx[i];
        #pragma unroll
        for (int off = 1; off < 16; off <<= 1) {
            float vb = __shfl_xor(b, off, 64);
            int   vi = __shfl_xor(bi, off, 64);
            if (vb < b || (vb == b && vi < bi)) { b = vb; bi = vi; }
        }
        best[i] = b; bidx[i] = bi;
    }
    if (kq == 0) {
        #pragma unroll
        for (int i = 0; i < 4; ++i)
            out_idx[n0 + rq * 4 + i] = (float)bidx[i];
    }

    // quantized output (fl(x + fl(q-x)) matches np bitwise) + fp64 loss partial
    double lacc = 0.0;
    #pragma unroll
    for (int i = 0; i < 4; ++i) {
        const int r = rq * 4 + i;
        const float4* qrow = cb4 + (size_t)bidx[i] * 64;
        #pragma unroll
        for (int m = 0; m < 4; ++m) {
            int d4 = kq + 16 * m;
            float4 q  = qrow[d4];
            float4 xv = xs4[r * 64 + d4];
            float dfx = __fsub_rn(q.x, xv.x);
            float dfy = __fsub_rn(q.y, xv.y);
            float dfz = __fsub_rn(q.z, xv.z);
            float dfw = __fsub_rn(q.w, xv.w);
            float4 o;
            o.x = __fadd_rn(xv.x, dfx);
            o.y = __fadd_rn(xv.y, dfy);
            o.z = __fadd_rn(xv.z, dfz);
            o.w = __fadd_rn(xv.w, dfw);
            lacc += (double)dfx * dfx + (double)dfy * dfy
                  + (double)dfz * dfz + (double)dfw * dfw;
            ((float4*)out_q)[(size_t)(n0 + r) * 64 + d4] = o;
        }
    }
    #pragma unroll
    for (int off = 32; off > 0; off >>= 1)
        lacc += __shfl_down(lacc, off, 64);
    if ((tid & 63) == 0) atomicAdd(loss_acc, lacc);
}

__global__ void finalize_loss(const double* __restrict__ acc,
                              float* __restrict__ out_loss) {
    if (threadIdx.x == 0 && blockIdx.x == 0)
        *out_loss = (float)(*acc / (double)(NROWS * DIM));
}

extern "C" void kernel_launch(void* const* d_in, const int* in_sizes, int n_in,
                              void* d_out, int out_size, void* d_ws, size_t ws_size,
                              hipStream_t stream) {
    const float* x  = (const float*)d_in[0];
    const float* cb = (const float*)d_in[1];
    float* out      = (float*)d_out;
    float* out_q    = out;                       // 8388608 elements
    float* out_idx  = out + (size_t)NROWS * DIM; // 32768 elements (as float)
    float* out_loss = out_idx + NROWS;           // 1 element

    double* acc = (double*)d_ws;
    float* se = (float*)((char*)d_ws + 8);
    float* sx = (float*)((char*)d_ws + 8 + 4096);

    init_ws<<<1, 1, 0, stream>>>(acc);
    rowsq_kernel<<<KCODES * 64 / (4 * 256) * 4, 256, 0, stream>>>(cb, se, KCODES); // 64 blocks
    rowsq_kernel<<<NROWS / 16, 256, 0, stream>>>(x, sx, NROWS);                    // 2048 blocks
    vq_main<<<NROWS / 64, 256, 0, stream>>>(x, cb, sx, se, out_q, out_idx, acc);
    finalize_loss<<<1, 1, 0, stream>>>(acc, out_loss);
}

// Round 3
// 359.618 us; speedup vs baseline: 2.7637x; 2.7637x over previous
//
#include <hip/hip_runtime.h>
#include <math.h>

#define NROWS 32768
#define DIM   256
#define KCODES 1024

// ws layout:
//   [0, 8)          double loss accumulator
//   [8, 8+4096)     se[1024]  float   (np-exact pairwise sum of codebook**2 rows)
//   [4104, +131072) sx[32768] float   (np-exact pairwise sum of x**2 rows)

__global__ void init_ws(double* acc) {
    if (threadIdx.x == 0 && blockIdx.x == 0) *acc = 0.0;
}

// Bit-exact replication of numpy pairwise_sum_FLOAT for n=256 contiguous floats
// (sum of squares of each row). See R0 notes: 8-acc blocked tree + butterfly.
__global__ void rowsq_kernel(const float* __restrict__ src,
                             float* __restrict__ dst, int nrows) {
    const int gtid = blockIdx.x * blockDim.x + threadIdx.x;
    const int wave = gtid >> 6;
    const int lane = threadIdx.x & 63;
    const int rowsub = lane >> 4;     // 0..3
    const int agent  = lane & 15;     // half*8 + j
    const int half   = agent >> 3;
    const int j      = agent & 7;
    const int row = wave * 4 + rowsub;
    if (row >= nrows) return;

    const float* p = src + (size_t)row * DIM + half * 128 + j;
    float x0 = p[0];
    float r = __fmul_rn(x0, x0);
    #pragma unroll
    for (int i = 1; i < 16; ++i) {
        float xi = p[8 * i];
        r = __fadd_rn(r, __fmul_rn(xi, xi));
    }
    r = __fadd_rn(r, __shfl_xor(r, 1, 64));
    r = __fadd_rn(r, __shfl_xor(r, 2, 64));
    r = __fadd_rn(r, __shfl_xor(r, 4, 64));
    r = __fadd_rn(r, __shfl_xor(r, 8, 64));
    if (agent == 0) dst[row] = r;
}

#define FMA4(A, X, E) do {                                       \
    A.x = fmaf(X.x, E.x, A.x); A.y = fmaf(X.y, E.y, A.y);        \
    A.z = fmaf(X.z, E.z, A.z); A.w = fmaf(X.w, E.w, A.w);        \
} while (0)

// Tile config: 64 rows/block, 8 passes of 128 codes, K chunked at 64 floats.
// LDS row stride 68 floats (272 B): 16B-aligned, 4-bank offset per row ->
// compute reads are broadcast/2-way (free). Micro-tile 4 rows x 8 codes.
__launch_bounds__(256, 2)
__global__ void vq_main(const float* __restrict__ x,
                        const float* __restrict__ cb,
                        const float* __restrict__ sx_arr,
                        const float* __restrict__ se_arr,
                        float* __restrict__ out_q,
                        float* __restrict__ out_idx,
                        double* __restrict__ loss_acc) {
    __shared__ __align__(16) float xs[64 * 68];    // 17408 B
    __shared__ __align__(16) float cs[128 * 68];   // 34816 B
    const int tid = threadIdx.x;
    const int n0  = blockIdx.x * 64;
    const int rg  = tid >> 4;   // 0..15: rows rg*4..rg*4+3
    const int cg  = tid & 15;   // 0..15: codes cg+16c within pass
    const float4* __restrict__ x4  = (const float4*)x;
    const float4* __restrict__ cb4 = (const float4*)cb;

    float sx[4], best[4];
    int bidx[4];
    #pragma unroll
    for (int r = 0; r < 4; ++r) {
        sx[r] = sx_arr[n0 + rg * 4 + r];
        best[r] = INFINITY;
        bidx[r] = 0;
    }

    for (int p = 0; p < 8; ++p) {
        float4 acc[4][8];
        #pragma unroll
        for (int r = 0; r < 4; ++r) {
            #pragma unroll
            for (int c = 0; c < 8; ++c) {
                acc[r][c] = make_float4(0.f, 0.f, 0.f, 0.f);
            }
        }

        for (int q = 0; q < 4; ++q) {
            __syncthreads();
            // stage x chunk: 64 rows x 16 float4 (coalesced)
            #pragma unroll
            for (int i = 0; i < 4; ++i) {
                int l = i * 256 + tid;
                int row = l >> 4, k4 = l & 15;
                float4 v = x4[(size_t)(n0 + row) * 64 + q * 16 + k4];
                *(float4*)(xs + row * 68 + k4 * 4) = v;
            }
            // stage codebook chunk: 128 codes x 16 float4 (coalesced)
            #pragma unroll
            for (int i = 0; i < 8; ++i) {
                int l = i * 256 + tid;
                int row = l >> 4, k4 = l & 15;
                float4 v = cb4[(size_t)(p * 128 + row) * 64 + q * 16 + k4];
                *(float4*)(cs + row * 68 + k4 * 4) = v;
            }
            __syncthreads();

            #pragma unroll
            for (int k4 = 0; k4 < 16; ++k4) {
                float4 xv[4], cv[8];
                #pragma unroll
                for (int r = 0; r < 4; ++r) {
                    xv[r] = *(const float4*)(xs + (rg * 4 + r) * 68 + k4 * 4);
                }
                #pragma unroll
                for (int c = 0; c < 8; ++c) {
                    cv[c] = *(const float4*)(cs + (cg + 16 * c) * 68 + k4 * 4);
                }
                #pragma unroll
                for (int r = 0; r < 4; ++r) {
                    #pragma unroll
                    for (int c = 0; c < 8; ++c) {
                        FMA4(acc[r][c], xv[r], cv[c]);
                    }
                }
            }
        }

        // per-pass argmin epilogue (codes ascending: c 0..7 -> kk ascending)
        #pragma unroll
        for (int c = 0; c < 8; ++c) {
            const int kk = p * 128 + cg + 16 * c;
            const float se = se_arr[kk];
            #pragma unroll
            for (int r = 0; r < 4; ++r) {
                float4 a = acc[r][c];
                float dot = (a.x + a.y) + (a.z + a.w);
                float t = __fadd_rn(sx[r], se);
                float dist = __fsub_rn(t, 2.0f * dot);
                if (dist < best[r]) { best[r] = dist; bidx[r] = kk; }
            }
        }
    }

    // cross-cg argmin reduce (16 lanes per row group, within-wave), tie -> lower k
    #pragma unroll
    for (int r = 0; r < 4; ++r) {
        float b = best[r]; int bi = bidx[r];
        #pragma unroll
        for (int off = 1; off < 16; off <<= 1) {
            float vb = __shfl_xor(b, off, 64);
            int   vi = __shfl_xor(bi, off, 64);
            if (vb < b || (vb == b && vi < bi)) { b = vb; bi = vi; }
        }
        best[r] = b; bidx[r] = bi;
    }
    if (cg == 0) {
        #pragma unroll
        for (int r = 0; r < 4; ++r) {
            out_idx[n0 + rg * 4 + r] = (float)bidx[r];
        }
    }

    // quantized output (fl(x + fl(q-x)) matches np bitwise) + fp64 loss partial
    double lacc = 0.0;
    #pragma unroll
    for (int r = 0; r < 4; ++r) {
        const int row = rg * 4 + r;
        const float4* qrow = cb4 + (size_t)bidx[r] * 64;
        #pragma unroll
        for (int m = 0; m < 4; ++m) {
            int d4 = cg + 16 * m;
            float4 qv = qrow[d4];
            float4 xv = x4[(size_t)(n0 + row) * 64 + d4];
            float dfx = __fsub_rn(qv.x, xv.x);
            float dfy = __fsub_rn(qv.y, xv.y);
            float dfz = __fsub_rn(qv.z, xv.z);
            float dfw = __fsub_rn(qv.w, xv.w);
            float4 o;
            o.x = __fadd_rn(xv.x, dfx);
            o.y = __fadd_rn(xv.y, dfy);
            o.z = __fadd_rn(xv.z, dfz);
            o.w = __fadd_rn(xv.w, dfw);
            lacc += (double)dfx * dfx + (double)dfy * dfy
                  + (double)dfz * dfz + (double)dfw * dfw;
            ((float4*)out_q)[(size_t)(n0 + row) * 64 + d4] = o;
        }
    }
    #pragma unroll
    for (int off = 32; off > 0; off >>= 1) {
        lacc += __shfl_down(lacc, off, 64);
    }
    if ((tid & 63) == 0) atomicAdd(loss_acc, lacc);
}

__global__ void finalize_loss(const double* __restrict__ acc,
                              float* __restrict__ out_loss) {
    if (threadIdx.x == 0 && blockIdx.x == 0)
        *out_loss = (float)(*acc / (double)(NROWS * DIM));
}

extern "C" void kernel_launch(void* const* d_in, const int* in_sizes, int n_in,
                              void* d_out, int out_size, void* d_ws, size_t ws_size,
                              hipStream_t stream) {
    const float* x  = (const float*)d_in[0];
    const float* cb = (const float*)d_in[1];
    float* out      = (float*)d_out;
    float* out_q    = out;                       // 8388608 elements
    float* out_idx  = out + (size_t)NROWS * DIM; // 32768 elements (as float)
    float* out_loss = out_idx + NROWS;           // 1 element

    double* acc = (double*)d_ws;
    float* se = (float*)((char*)d_ws + 8);
    float* sx = (float*)((char*)d_ws + 8 + 4096);

    init_ws<<<1, 1, 0, stream>>>(acc);
    rowsq_kernel<<<64, 256, 0, stream>>>(cb, se, KCODES);
    rowsq_kernel<<<NROWS / 16, 256, 0, stream>>>(x, sx, NROWS);
    vq_main<<<NROWS / 64, 256, 0, stream>>>(x, cb, sx, se, out_q, out_idx, acc);
    finalize_loss<<<1, 1, 0, stream>>>(acc, out_loss);
}